// Round 1
// baseline (258.331 us; speedup 1.0000x reference)
//
#include <hip/hip_runtime.h>
#include <hip/hip_bf16.h>

// B=4, S=2048, D=512, H=8, DK=DV=64. All heads identical; V projected from
// `key` (faithful bug). tile(o,H)@Wo == o@WoE, WoE[j,d] = sum_h Wo[h*64+j,d].
// Softmax in exp2 domain with FIXED shift M=8. 0.125*log2(e) folded into
// Wq/bq at prep time.
//
// THIS VERSION: all four previously-verified kernels fused into ONE
// persistent kernel with device-scope grid barriers between phases.
// Phase bodies are identical to the verified 4-kernel version; only the
// orchestration changed (goal: eliminate inter-dispatch gaps/launch
// overhead, and expose whole-pipeline counters in one dispatch).

#define BB 4
#define SS 2048
#define BS (BB*SS)   // 8192
#define MSHIFT 8.0f
#define NCH 8        // attention chunks (workspace is ample)
#define NVB 1024     // virtual blocks per phase

typedef __bf16 v8bf __attribute__((ext_vector_type(8)));
typedef __bf16 v4bf __attribute__((ext_vector_type(4)));
typedef float  v4f  __attribute__((ext_vector_type(4)));

__device__ inline v8bf cvt8(float4 f0, float4 f1) {   // native v_cvt (RNE)
    v8bf r;
    r[0] = (__bf16)f0.x; r[1] = (__bf16)f0.y; r[2] = (__bf16)f0.z; r[3] = (__bf16)f0.w;
    r[4] = (__bf16)f1.x; r[5] = (__bf16)f1.y; r[6] = (__bf16)f1.z; r[7] = (__bf16)f1.w;
    return r;
}

// Generation-counter grid barrier, agent scope. bar[0]=arrive count,
// bar[1]=generation. Zeroed per launch by hipMemsetAsync (poison-safe).
// Release/acquire chain: arriver fetch_add(ACQ_REL) -> last arriver
// store gen+1 (RELEASE) -> waiters load (ACQUIRE). Bounded spin turns a
// (never-expected) residency failure into a wrong answer, not a hang.
__device__ __forceinline__ void grid_sync(unsigned* bar) {
    __syncthreads();
    if (threadIdx.x == 0) {
        const unsigned nb = gridDim.x;
        unsigned gen = __hip_atomic_load(&bar[1], __ATOMIC_RELAXED, __HIP_MEMORY_SCOPE_AGENT);
        unsigned arr = __hip_atomic_fetch_add(&bar[0], 1u, __ATOMIC_ACQ_REL, __HIP_MEMORY_SCOPE_AGENT);
        if (arr == nb - 1u) {
            __hip_atomic_store(&bar[0], 0u, __ATOMIC_RELAXED, __HIP_MEMORY_SCOPE_AGENT);
            __hip_atomic_store(&bar[1], gen + 1u, __ATOMIC_RELEASE, __HIP_MEMORY_SCOPE_AGENT);
        } else {
            unsigned spins = 0;
            while (__hip_atomic_load(&bar[1], __ATOMIC_ACQUIRE, __HIP_MEMORY_SCOPE_AGENT) == gen) {
                __builtin_amdgcn_s_sleep(1);
                if (++spins > (1u << 22)) break;   // failsafe: fail clean, not hung
            }
        }
    }
    __syncthreads();
}

__global__ __launch_bounds__(256) void fused_kernel(
    const float* __restrict__ query, const float* __restrict__ key,
    const float* __restrict__ Wq, const float* __restrict__ bq,
    const float* __restrict__ Wk, const float* __restrict__ bk,
    const float* __restrict__ Wv, const float* __restrict__ bv,
    const float* __restrict__ Wo, const float* __restrict__ bo,
    __bf16* __restrict__ Qp, __bf16* __restrict__ Kp, __bf16* __restrict__ Vt,
    __bf16* __restrict__ Opart, float* __restrict__ lpart,
    __bf16* __restrict__ WoEt, __bf16* __restrict__ Wt, float* __restrict__ bs,
    float* __restrict__ out, unsigned* bar)
{
    __shared__ __bf16 Ks[64][72];
    __shared__ __bf16 Vs[64][72];
    __shared__ __bf16 Ps[4][16][72];

    const int t    = threadIdx.x;
    const int nb   = gridDim.x;
    const int lane = t & 63;
    const int w    = t >> 6;
    const int lq   = lane & 15;
    const int quad = lane >> 4;

    // ================================================== phase 0: weight prep
    // 131072 items: y<3: Wt[y][c][k] = W_y[k][c] (*scale for Q); y==3: WoEt.
    for (int item = blockIdx.x * 256 + t; item < 131072; item += nb * 256) {
        if (item < 98304) {
            int y = item >> 15, idx = item & 32767;
            const float* W  = (y == 0) ? Wq : (y == 1) ? Wk : Wv;
            const float* bb = (y == 0) ? bq : (y == 1) ? bk : bv;
            const float s = (y == 0) ? (0.125f * 1.44269504088896340736f) : 1.0f;
            int c = idx & 63, k = idx >> 6;
            Wt[y * 32768 + c * 512 + k] = (__bf16)(W[k * 64 + c] * s);
            if (idx < 64) bs[y * 64 + idx] = bb[idx] * s;
        } else {
            int idx = item - 98304;
            int d = idx & 511, k = idx >> 9;
            float sum = 0.f;
#pragma unroll
            for (int h = 0; h < 8; h++) sum += Wo[(size_t)(h * 64 + k) * 512 + d];
            WoEt[d * 64 + k] = (__bf16)sum;
        }
    }
    grid_sync(bar);

    // ================================================== phase 1: QKV projection
    for (int vb = blockIdx.x; vb < NVB; vb += nb) {
        const int gw   = vb * 4 + w;                   // 0..4095
        const int kind = gw >> 11;                     // 0=Q, 1=K+V
        const int rr   = gw & 2047;
        const int rows = (rr >> 2) * 16;
        const int cb   = (rr & 3) * 16;
        const float* arow = ((kind == 0) ? query : key) + (size_t)(rows + lq) * 512;

        if (kind == 0) {
            const __bf16* W = Wt + (cb + lq) * 512;
            const float bb = bs[cb + lq];
            v4f acc = {bb, bb, bb, bb};
#pragma unroll 4
            for (int k0 = 0; k0 < 512; k0 += 32) {
                float4 f0 = *(const float4*)(arow + k0 + quad * 8);
                float4 f1 = *(const float4*)(arow + k0 + quad * 8 + 4);
                v8bf a = cvt8(f0, f1);
                v8bf b = *(const v8bf*)(W + k0 + quad * 8);
                acc = __builtin_amdgcn_mfma_f32_16x16x32_bf16(a, b, acc, 0, 0, 0);
            }
#pragma unroll
            for (int r = 0; r < 4; r++)
                Qp[(size_t)(rows + quad * 4 + r) * 64 + cb + lq] = (__bf16)acc[r];
        } else {
            const __bf16* Wk_ = Wt + 32768 + (cb + lq) * 512;
            const __bf16* Wv_ = Wt + 65536 + (cb + lq) * 512;
            const float bk_ = bs[64 + cb + lq], bv_ = bs[128 + cb + lq];
            v4f ak = {bk_, bk_, bk_, bk_}, av = {bv_, bv_, bv_, bv_};
#pragma unroll 4
            for (int k0 = 0; k0 < 512; k0 += 32) {
                float4 f0 = *(const float4*)(arow + k0 + quad * 8);
                float4 f1 = *(const float4*)(arow + k0 + quad * 8 + 4);
                v8bf a  = cvt8(f0, f1);
                v8bf b0 = *(const v8bf*)(Wk_ + k0 + quad * 8);
                v8bf b1 = *(const v8bf*)(Wv_ + k0 + quad * 8);
                ak = __builtin_amdgcn_mfma_f32_16x16x32_bf16(a, b0, ak, 0, 0, 0);
                av = __builtin_amdgcn_mfma_f32_16x16x32_bf16(a, b1, av, 0, 0, 0);
            }
#pragma unroll
            for (int r = 0; r < 4; r++)
                Kp[(size_t)(rows + quad * 4 + r) * 64 + cb + lq] = (__bf16)ak[r];
            v4bf o4; o4[0] = (__bf16)av[0]; o4[1] = (__bf16)av[1];
            o4[2] = (__bf16)av[2]; o4[3] = (__bf16)av[3];
            *(v4bf*)&Vt[(size_t)(cb + lq) * BS + rows + quad * 4] = o4;   // V^T
        }
    }
    grid_sync(bar);

    // ================================================== phase 2: flash attention
    {
        v8bf ones;
#pragma unroll
        for (int i = 0; i < 8; i++) ones[i] = (__bf16)1.0f;

        for (int vb = blockIdx.x; vb < NVB; vb += nb) {
            const int x  = vb & 127;
            const int ch = vb >> 7;                    // chunk 0..7
            const int b  = x & 3;
            const int qt = 31 - (x >> 2);              // longest work first
            const int qbase = qt * 64;
            const int L   = qbase + 64;
            const int cs  = ((L + NCH * 64 - 1) / (NCH * 64)) * 64;
            const int klo = ch * cs;
            const int khi = min(klo + cs, L);          // multiple of 64
            const size_t bbase = (size_t)b * SS;

            const int qrow_w = qbase + w * 16;
            const int wmax   = qrow_w + 15;

            const size_t qoff = (bbase + qrow_w + lq) * 64;
            v8bf qa0 = *(const v8bf*)(Qp + qoff + quad * 8);
            v8bf qa1 = *(const v8bf*)(Qp + qoff + 32 + quad * 8);

            v4f o[4] = {};
            v4f lacc = {};

            const int ky0 = t >> 3,         dd0 = (t & 7) * 8;   // rows 0..31
            const int ky1 = (t + 256) >> 3, dd1 = dd0;           // rows 32..63

            v8bf kpre0, kpre1, vpre0, vpre1;
            if (klo < khi) {
                kpre0 = *(const v8bf*)(Kp + (bbase + klo + ky0) * 64 + dd0);
                kpre1 = *(const v8bf*)(Kp + (bbase + klo + ky1) * 64 + dd1);
                vpre0 = *(const v8bf*)(Vt + (size_t)ky0 * BS + bbase + klo + dd0);
                vpre1 = *(const v8bf*)(Vt + (size_t)ky1 * BS + bbase + klo + dd1);
            }

            for (int kb = klo; kb < khi; kb += 64) {
                __syncthreads();                       // previous tile's readers done
                *(v8bf*)&Ks[ky0][dd0] = kpre0;
                *(v8bf*)&Ks[ky1][dd1] = kpre1;
                *(v8bf*)&Vs[ky0][dd0] = vpre0;
                *(v8bf*)&Vs[ky1][dd1] = vpre1;
                if (kb + 64 < khi) {                   // prefetch next tile
                    kpre0 = *(const v8bf*)(Kp + (bbase + kb + 64 + ky0) * 64 + dd0);
                    kpre1 = *(const v8bf*)(Kp + (bbase + kb + 64 + ky1) * 64 + dd1);
                    vpre0 = *(const v8bf*)(Vt + (size_t)ky0 * BS + bbase + kb + 64 + dd0);
                    vpre1 = *(const v8bf*)(Vt + (size_t)ky1 * BS + bbase + kb + 64 + dd1);
                }
                __syncthreads();
                if (kb > wmax) continue;               // wave fully masked (uniform)

                // ---- S = Q K^T
                v4f s[4];
#pragma unroll
                for (int n = 0; n < 4; n++) {
                    v8bf ka  = *(const v8bf*)&Ks[n * 16 + lq][quad * 8];
                    v8bf kb2 = *(const v8bf*)&Ks[n * 16 + lq][32 + quad * 8];
                    v4f z = {0.f, 0.f, 0.f, 0.f};
                    z    = __builtin_amdgcn_mfma_f32_16x16x32_bf16(qa0, ka,  z, 0, 0, 0);
                    s[n] = __builtin_amdgcn_mfma_f32_16x16x32_bf16(qa1, kb2, z, 0, 0, 0);
                }

                // ---- P = exp2(s - 8), causal-masked; to LDS (C->A relayout)
                const int row0 = qrow_w + quad * 4;
                const int col0 = kb + lq;
#pragma unroll
                for (int n = 0; n < 4; n++)
#pragma unroll
                    for (int r = 0; r < 4; r++) {
                        float e = exp2f(s[n][r] - MSHIFT);
                        e = (col0 + n * 16 > row0 + r) ? 0.f : e;
                        Ps[w][quad * 4 + r][n * 16 + lq] = (__bf16)e;
                    }
                v8bf pa0 = *(const v8bf*)&Ps[w][lq][quad * 8];
                v8bf pa1 = *(const v8bf*)&Ps[w][lq][32 + quad * 8];

                // ---- l += P @ ones
                lacc = __builtin_amdgcn_mfma_f32_16x16x32_bf16(pa0, ones, lacc, 0, 0, 0);
                lacc = __builtin_amdgcn_mfma_f32_16x16x32_bf16(pa1, ones, lacc, 0, 0, 0);

                // ---- O += P V
#pragma unroll
                for (int vt2 = 0; vt2 < 4; vt2++) {
                    v8bf vb0 = *(const v8bf*)&Vs[vt2 * 16 + lq][quad * 8];
                    v8bf vb1 = *(const v8bf*)&Vs[vt2 * 16 + lq][32 + quad * 8];
                    o[vt2] = __builtin_amdgcn_mfma_f32_16x16x32_bf16(pa0, vb0, o[vt2], 0, 0, 0);
                    o[vt2] = __builtin_amdgcn_mfma_f32_16x16x32_bf16(pa1, vb1, o[vt2], 0, 0, 0);
                }
            }

            // ---- write partials (empty chunks write o=0, l=0 — merge-neutral)
#pragma unroll
            for (int vt2 = 0; vt2 < 4; vt2++)
#pragma unroll
                for (int r = 0; r < 4; r++) {
                    int qrow = qrow_w + quad * 4 + r;
                    Opart[((size_t)ch * BS + bbase + qrow) * 64 + vt2 * 16 + lq] = (__bf16)o[vt2][r];
                }
            if (lq < 4) {
                int qrow = qrow_w + quad * 4 + lq;
                lpart[(size_t)ch * BS + bbase + qrow] = lacc[lq];
            }
        }
    }
    grid_sync(bar);

    // ================================================== phase 3: merge + out-GEMM
    // 1024 vblocks: vb&511 selects 16-row group, vb>>9 selects column half
    // (4 of 8 out-tiles per wave) — halves last-phase critical path.
    {
        __bf16 (&Os)[64][72] = Ks;                     // reuse LDS
        for (int vb = blockIdx.x; vb < NVB; vb += nb) {
            __syncthreads();                           // protect Os reuse across iters
            const int rows0 = (vb & 511) * 16;
            const int half  = vb >> 9;
            {
                int row = t >> 4, d0 = (t & 15) * 4;
                float den = 0.f;
                for (int c2 = 0; c2 < NCH; c2++) den += lpart[(size_t)c2 * BS + rows0 + row];
                const float inv = 1.f / den;
                float a0 = 0.f, a1 = 0.f, a2 = 0.f, a3 = 0.f;
                for (int c2 = 0; c2 < NCH; c2++) {
                    v4bf v = *(const v4bf*)&Opart[((size_t)c2 * BS + rows0 + row) * 64 + d0];
                    a0 += (float)v[0]; a1 += (float)v[1]; a2 += (float)v[2]; a3 += (float)v[3];
                }
                Os[row][d0] = (__bf16)(a0 * inv); Os[row][d0 + 1] = (__bf16)(a1 * inv);
                Os[row][d0 + 2] = (__bf16)(a2 * inv); Os[row][d0 + 3] = (__bf16)(a3 * inv);
            }
            __syncthreads();

            v8bf a0 = *(const v8bf*)&Os[lq][quad * 8];
            v8bf a1 = *(const v8bf*)&Os[lq][32 + quad * 8];
#pragma unroll
            for (int i = 0; i < 4; i++) {
                const int cb = (w * 8 + half * 4 + i) * 16;
                v8bf b0 = *(const v8bf*)(WoEt + (size_t)(cb + lq) * 64 + quad * 8);
                v8bf b1 = *(const v8bf*)(WoEt + (size_t)(cb + lq) * 64 + 32 + quad * 8);
                const float bb = bo[cb + lq];
                v4f acc = {bb, bb, bb, bb};
                acc = __builtin_amdgcn_mfma_f32_16x16x32_bf16(a0, b0, acc, 0, 0, 0);
                acc = __builtin_amdgcn_mfma_f32_16x16x32_bf16(a1, b1, acc, 0, 0, 0);
#pragma unroll
                for (int r = 0; r < 4; r++)
                    out[(size_t)(rows0 + quad * 4 + r) * 512 + cb + lq] = acc[r];
            }
        }
    }
}

// ---------------------------------------------------------------- launch
extern "C" void kernel_launch(void* const* d_in, const int* in_sizes, int n_in,
                              void* d_out, int out_size, void* d_ws, size_t ws_size,
                              hipStream_t stream) {
    const float* query = (const float*)d_in[0];
    const float* key   = (const float*)d_in[1];
    // d_in[2] (value) unused: reference projects V from `key`.
    const float* Wq = (const float*)d_in[3];
    const float* bq = (const float*)d_in[4];
    const float* Wk = (const float*)d_in[5];
    const float* bk = (const float*)d_in[6];
    const float* Wv = (const float*)d_in[7];
    const float* bv = (const float*)d_in[8];
    const float* Wo = (const float*)d_in[9];
    const float* bo = (const float*)d_in[10];
    float* out = (float*)d_out;

    char* p = (char*)d_ws;
    __bf16* Qp    = (__bf16*)p; p += (size_t)BS * 64 * 2;          // 1 MB
    __bf16* Kp    = (__bf16*)p; p += (size_t)BS * 64 * 2;          // 1 MB
    __bf16* Vtg   = (__bf16*)p; p += (size_t)BS * 64 * 2;          // 1 MB
    __bf16* Opart = (__bf16*)p; p += (size_t)NCH * BS * 64 * 2;    // 8 MB
    float* lpart = (float*)p;  p += (size_t)NCH * BS * 4;          // 256 KB
    __bf16* WoEt = (__bf16*)p; p += (size_t)64 * 512 * 2;          // 64 KB
    __bf16* Wt   = (__bf16*)p; p += (size_t)3 * 64 * 512 * 2;      // 192 KB
    float* bs    = (float*)p;  p += 768;
    uintptr_t pa = ((uintptr_t)p + 255) & ~(uintptr_t)255;
    unsigned* bar = (unsigned*)pa;                                  // 64 B barrier state

    // Grid sized to guaranteed co-residency (barrier correctness). Host-only
    // occupancy query, cached; safe under graph capture.
    static int nb_s = 0;
    if (nb_s == 0) {
        int perCU = 0;
        if (hipOccupancyMaxActiveBlocksPerMultiprocessor(
                &perCU, reinterpret_cast<const void*>(fused_kernel), 256, 0) != hipSuccess
            || perCU < 1)
            perCU = 1;                                  // 1 block/CU always resident
        nb_s = perCU * 256;                             // 256 CUs on MI355X
        if (nb_s > NVB) nb_s = NVB;
    }

    hipMemsetAsync(bar, 0, 64, stream);                 // reset barrier each launch
    fused_kernel<<<nb_s, 256, 0, stream>>>(
        query, key, Wq, bq, Wk, bk, Wv, bv, Wo, bo,
        Qp, Kp, Vtg, Opart, lpart, WoEt, Wt, bs, out, bar);
}

// Round 3
// 237.624 us; speedup vs baseline: 1.0871x; 1.0871x over previous
//
#include <hip/hip_runtime.h>
#include <hip/hip_bf16.h>

// B=4, S=2048, D=512, H=8, DK=DV=64. All heads identical; V projected from
// `key` (faithful bug). tile(o,H)@Wo == o@WoE, WoE[j,d] = sum_h Wo[h*64+j,d].
// Softmax in exp2 domain with FIXED shift M=8. 0.125*log2(e) folded into
// Wq/bq at prep time.
//
// Persistent fused kernel, v3: Round-1's single-cacheline fetch_add barrier
// cost ~100us/barrier (1024 serialized cross-XCD RMWs on one line;
// MfmaUtil 0.47%, VALUBusy 1.9% == GPU idle in the barrier). Replaced by a
// distributed-flag barrier built ONLY from __hip_atomic_load/store with
// release/acquire orderings (this ROCm lacks __hip_atomic_fence; Round 1
// proved load/store/fetch_add compile and work at agent scope).
// Phase bodies unchanged (harness-verified).

#define BB 4
#define SS 2048
#define BS (BB*SS)   // 8192
#define MSHIFT 8.0f
#define NCH 8        // attention chunks
#define NVB 1024     // virtual blocks per phase

typedef __bf16 v8bf __attribute__((ext_vector_type(8)));
typedef __bf16 v4bf __attribute__((ext_vector_type(4)));
typedef float  v4f  __attribute__((ext_vector_type(4)));

__device__ inline v8bf cvt8(float4 f0, float4 f1) {   // native v_cvt (RNE)
    v8bf r;
    r[0] = (__bf16)f0.x; r[1] = (__bf16)f0.y; r[2] = (__bf16)f0.z; r[3] = (__bf16)f0.w;
    r[4] = (__bf16)f1.x; r[5] = (__bf16)f1.y; r[6] = (__bf16)f1.z; r[7] = (__bf16)f1.w;
    return r;
}

// Distributed-flag grid barrier, generation g = 1,2,3...
// bar[0] (own cacheline) = published generation. flags[] at byte offset 256,
// one u32 per block. Arrival: RELEASE store to OWN slot (parallel, no
// cross-block contention). Block 0 wave 0 polls all flags with ACQUIRE
// loads (coalesced, 16/lane/round), then RELEASE-stores the generation
// word; waiters spin on ACQUIRE loads of it (the exact pattern Round 1
// compiled + ran). Happens-before is transitive through block 0, so each
// phase's global writes are visible across XCDs after the barrier.
// Bounded spins: a residency failure becomes a wrong answer, not a hang.
__device__ __forceinline__ void grid_sync(unsigned* bar, unsigned g) {
    __syncthreads();
    unsigned* flags = bar + 64;                      // +256 B
    const int nb = (int)gridDim.x;
    if (threadIdx.x == 0) {
        __hip_atomic_store(&flags[blockIdx.x], g, __ATOMIC_RELEASE, __HIP_MEMORY_SCOPE_AGENT);
    }
    if (blockIdx.x == 0) {
        if (threadIdx.x < 64) {
            unsigned spins = 0;
            for (;;) {
                int ok = 1;
                for (int i = threadIdx.x; i < nb; i += 64)
                    ok &= (__hip_atomic_load(&flags[i], __ATOMIC_ACQUIRE,
                                             __HIP_MEMORY_SCOPE_AGENT) >= g);
                if (__all(ok)) break;
                __builtin_amdgcn_s_sleep(2);
                if (++spins > (1u << 18)) break;     // failsafe
            }
        }
        __syncthreads();                              // whole block 0 knows
        if (threadIdx.x == 0) {
            __hip_atomic_store(&bar[0], g, __ATOMIC_RELEASE, __HIP_MEMORY_SCOPE_AGENT);
        }
    } else if (threadIdx.x == 0) {
        unsigned spins = 0;
        while (__hip_atomic_load(&bar[0], __ATOMIC_ACQUIRE,
                                 __HIP_MEMORY_SCOPE_AGENT) < g) {
            __builtin_amdgcn_s_sleep(16);            // ~430 cy poll backoff
            if (++spins > (1u << 18)) break;         // failsafe
        }
    }
    __syncthreads();
}

__global__ __launch_bounds__(256) void fused_kernel(
    const float* __restrict__ query, const float* __restrict__ key,
    const float* __restrict__ Wq, const float* __restrict__ bq,
    const float* __restrict__ Wk, const float* __restrict__ bk,
    const float* __restrict__ Wv, const float* __restrict__ bv,
    const float* __restrict__ Wo, const float* __restrict__ bo,
    __bf16* __restrict__ Qp, __bf16* __restrict__ Kp, __bf16* __restrict__ Vt,
    __bf16* __restrict__ Opart, float* __restrict__ lpart,
    __bf16* __restrict__ WoEt, __bf16* __restrict__ Wt, float* __restrict__ bs,
    float* __restrict__ out, unsigned* bar)
{
    __shared__ __bf16 Ks[64][72];
    __shared__ __bf16 Vs[64][72];
    __shared__ __bf16 Ps[4][16][72];

    const int t    = threadIdx.x;
    const int nb   = gridDim.x;
    const int lane = t & 63;
    const int w    = t >> 6;
    const int lq   = lane & 15;
    const int quad = lane >> 4;

    // ================================================== phase 0: weight prep
    for (int item = blockIdx.x * 256 + t; item < 131072; item += nb * 256) {
        if (item < 98304) {
            int y = item >> 15, idx = item & 32767;
            const float* W  = (y == 0) ? Wq : (y == 1) ? Wk : Wv;
            const float* bb = (y == 0) ? bq : (y == 1) ? bk : bv;
            const float s = (y == 0) ? (0.125f * 1.44269504088896340736f) : 1.0f;
            int c = idx & 63, k = idx >> 6;
            Wt[y * 32768 + c * 512 + k] = (__bf16)(W[k * 64 + c] * s);
            if (idx < 64) bs[y * 64 + idx] = bb[idx] * s;
        } else {
            int idx = item - 98304;
            int d = idx & 511, k = idx >> 9;
            float sum = 0.f;
#pragma unroll
            for (int h = 0; h < 8; h++) sum += Wo[(size_t)(h * 64 + k) * 512 + d];
            WoEt[d * 64 + k] = (__bf16)sum;
        }
    }
    grid_sync(bar, 1u);

    // ================================================== phase 1: QKV projection
    for (int vb = blockIdx.x; vb < NVB; vb += nb) {
        const int gw   = vb * 4 + w;                   // 0..4095
        const int kind = gw >> 11;                     // 0=Q, 1=K+V
        const int rr   = gw & 2047;
        const int rows = (rr >> 2) * 16;
        const int cb   = (rr & 3) * 16;
        const float* arow = ((kind == 0) ? query : key) + (size_t)(rows + lq) * 512;

        if (kind == 0) {
            const __bf16* W = Wt + (cb + lq) * 512;
            const float bb = bs[cb + lq];
            v4f acc = {bb, bb, bb, bb};
#pragma unroll 4
            for (int k0 = 0; k0 < 512; k0 += 32) {
                float4 f0 = *(const float4*)(arow + k0 + quad * 8);
                float4 f1 = *(const float4*)(arow + k0 + quad * 8 + 4);
                v8bf a = cvt8(f0, f1);
                v8bf b = *(const v8bf*)(W + k0 + quad * 8);
                acc = __builtin_amdgcn_mfma_f32_16x16x32_bf16(a, b, acc, 0, 0, 0);
            }
#pragma unroll
            for (int r = 0; r < 4; r++)
                Qp[(size_t)(rows + quad * 4 + r) * 64 + cb + lq] = (__bf16)acc[r];
        } else {
            const __bf16* Wk_ = Wt + 32768 + (cb + lq) * 512;
            const __bf16* Wv_ = Wt + 65536 + (cb + lq) * 512;
            const float bk_ = bs[64 + cb + lq], bv_ = bs[128 + cb + lq];
            v4f ak = {bk_, bk_, bk_, bk_}, av = {bv_, bv_, bv_, bv_};
#pragma unroll 4
            for (int k0 = 0; k0 < 512; k0 += 32) {
                float4 f0 = *(const float4*)(arow + k0 + quad * 8);
                float4 f1 = *(const float4*)(arow + k0 + quad * 8 + 4);
                v8bf a  = cvt8(f0, f1);
                v8bf b0 = *(const v8bf*)(Wk_ + k0 + quad * 8);
                v8bf b1 = *(const v8bf*)(Wv_ + k0 + quad * 8);
                ak = __builtin_amdgcn_mfma_f32_16x16x32_bf16(a, b0, ak, 0, 0, 0);
                av = __builtin_amdgcn_mfma_f32_16x16x32_bf16(a, b1, av, 0, 0, 0);
            }
#pragma unroll
            for (int r = 0; r < 4; r++)
                Kp[(size_t)(rows + quad * 4 + r) * 64 + cb + lq] = (__bf16)ak[r];
            v4bf o4; o4[0] = (__bf16)av[0]; o4[1] = (__bf16)av[1];
            o4[2] = (__bf16)av[2]; o4[3] = (__bf16)av[3];
            *(v4bf*)&Vt[(size_t)(cb + lq) * BS + rows + quad * 4] = o4;   // V^T
        }
    }
    grid_sync(bar, 2u);

    // ================================================== phase 2: flash attention
    {
        v8bf ones;
#pragma unroll
        for (int i = 0; i < 8; i++) ones[i] = (__bf16)1.0f;

        for (int vb = blockIdx.x; vb < NVB; vb += nb) {
            const int x  = vb & 127;
            const int ch = vb >> 7;                    // chunk 0..7
            const int b  = x & 3;
            const int qt = 31 - (x >> 2);              // longest work first
            const int qbase = qt * 64;
            const int L   = qbase + 64;
            const int cs  = ((L + NCH * 64 - 1) / (NCH * 64)) * 64;
            const int klo = ch * cs;
            const int khi = min(klo + cs, L);          // multiple of 64
            const size_t bbase = (size_t)b * SS;

            const int qrow_w = qbase + w * 16;
            const int wmax   = qrow_w + 15;

            const size_t qoff = (bbase + qrow_w + lq) * 64;
            v8bf qa0 = *(const v8bf*)(Qp + qoff + quad * 8);
            v8bf qa1 = *(const v8bf*)(Qp + qoff + 32 + quad * 8);

            v4f o[4] = {};
            v4f lacc = {};

            const int ky0 = t >> 3,         dd0 = (t & 7) * 8;   // rows 0..31
            const int ky1 = (t + 256) >> 3, dd1 = dd0;           // rows 32..63

            v8bf kpre0, kpre1, vpre0, vpre1;
            if (klo < khi) {
                kpre0 = *(const v8bf*)(Kp + (bbase + klo + ky0) * 64 + dd0);
                kpre1 = *(const v8bf*)(Kp + (bbase + klo + ky1) * 64 + dd1);
                vpre0 = *(const v8bf*)(Vt + (size_t)ky0 * BS + bbase + klo + dd0);
                vpre1 = *(const v8bf*)(Vt + (size_t)ky1 * BS + bbase + klo + dd1);
            }

            for (int kb = klo; kb < khi; kb += 64) {
                __syncthreads();                       // previous tile's readers done
                *(v8bf*)&Ks[ky0][dd0] = kpre0;
                *(v8bf*)&Ks[ky1][dd1] = kpre1;
                *(v8bf*)&Vs[ky0][dd0] = vpre0;
                *(v8bf*)&Vs[ky1][dd1] = vpre1;
                if (kb + 64 < khi) {                   // prefetch next tile
                    kpre0 = *(const v8bf*)(Kp + (bbase + kb + 64 + ky0) * 64 + dd0);
                    kpre1 = *(const v8bf*)(Kp + (bbase + kb + 64 + ky1) * 64 + dd1);
                    vpre0 = *(const v8bf*)(Vt + (size_t)ky0 * BS + bbase + kb + 64 + dd0);
                    vpre1 = *(const v8bf*)(Vt + (size_t)ky1 * BS + bbase + kb + 64 + dd1);
                }
                __syncthreads();
                if (kb > wmax) continue;               // wave fully masked (uniform)

                // ---- S = Q K^T
                v4f s[4];
#pragma unroll
                for (int n = 0; n < 4; n++) {
                    v8bf ka  = *(const v8bf*)&Ks[n * 16 + lq][quad * 8];
                    v8bf kb2 = *(const v8bf*)&Ks[n * 16 + lq][32 + quad * 8];
                    v4f z = {0.f, 0.f, 0.f, 0.f};
                    z    = __builtin_amdgcn_mfma_f32_16x16x32_bf16(qa0, ka,  z, 0, 0, 0);
                    s[n] = __builtin_amdgcn_mfma_f32_16x16x32_bf16(qa1, kb2, z, 0, 0, 0);
                }

                // ---- P = exp2(s - 8), causal-masked; to LDS (C->A relayout)
                const int row0 = qrow_w + quad * 4;
                const int col0 = kb + lq;
#pragma unroll
                for (int n = 0; n < 4; n++)
#pragma unroll
                    for (int r = 0; r < 4; r++) {
                        float e = exp2f(s[n][r] - MSHIFT);
                        e = (col0 + n * 16 > row0 + r) ? 0.f : e;
                        Ps[w][quad * 4 + r][n * 16 + lq] = (__bf16)e;
                    }
                v8bf pa0 = *(const v8bf*)&Ps[w][lq][quad * 8];
                v8bf pa1 = *(const v8bf*)&Ps[w][lq][32 + quad * 8];

                // ---- l += P @ ones
                lacc = __builtin_amdgcn_mfma_f32_16x16x32_bf16(pa0, ones, lacc, 0, 0, 0);
                lacc = __builtin_amdgcn_mfma_f32_16x16x32_bf16(pa1, ones, lacc, 0, 0, 0);

                // ---- O += P V
#pragma unroll
                for (int vt2 = 0; vt2 < 4; vt2++) {
                    v8bf vb0 = *(const v8bf*)&Vs[vt2 * 16 + lq][quad * 8];
                    v8bf vb1 = *(const v8bf*)&Vs[vt2 * 16 + lq][32 + quad * 8];
                    o[vt2] = __builtin_amdgcn_mfma_f32_16x16x32_bf16(pa0, vb0, o[vt2], 0, 0, 0);
                    o[vt2] = __builtin_amdgcn_mfma_f32_16x16x32_bf16(pa1, vb1, o[vt2], 0, 0, 0);
                }
            }

            // ---- write partials (empty chunks write o=0, l=0 — merge-neutral)
#pragma unroll
            for (int vt2 = 0; vt2 < 4; vt2++)
#pragma unroll
                for (int r = 0; r < 4; r++) {
                    int qrow = qrow_w + quad * 4 + r;
                    Opart[((size_t)ch * BS + bbase + qrow) * 64 + vt2 * 16 + lq] = (__bf16)o[vt2][r];
                }
            if (lq < 4) {
                int qrow = qrow_w + quad * 4 + lq;
                lpart[(size_t)ch * BS + bbase + qrow] = lacc[lq];
            }
        }
    }
    grid_sync(bar, 3u);

    // ================================================== phase 3: merge + out-GEMM
    {
        __bf16 (&Os)[64][72] = Ks;                     // reuse LDS
        for (int vb = blockIdx.x; vb < NVB; vb += nb) {
            __syncthreads();                           // protect Os reuse across iters
            const int rows0 = (vb & 511) * 16;
            const int half  = vb >> 9;
            {
                int row = t >> 4, d0 = (t & 15) * 4;
                float den = 0.f;
                for (int c2 = 0; c2 < NCH; c2++) den += lpart[(size_t)c2 * BS + rows0 + row];
                const float inv = 1.f / den;
                float a0 = 0.f, a1 = 0.f, a2 = 0.f, a3 = 0.f;
                for (int c2 = 0; c2 < NCH; c2++) {
                    v4bf v = *(const v4bf*)&Opart[((size_t)c2 * BS + rows0 + row) * 64 + d0];
                    a0 += (float)v[0]; a1 += (float)v[1]; a2 += (float)v[2]; a3 += (float)v[3];
                }
                Os[row][d0] = (__bf16)(a0 * inv); Os[row][d0 + 1] = (__bf16)(a1 * inv);
                Os[row][d0 + 2] = (__bf16)(a2 * inv); Os[row][d0 + 3] = (__bf16)(a3 * inv);
            }
            __syncthreads();

            v8bf a0 = *(const v8bf*)&Os[lq][quad * 8];
            v8bf a1 = *(const v8bf*)&Os[lq][32 + quad * 8];
#pragma unroll
            for (int i = 0; i < 4; i++) {
                const int cb = (w * 8 + half * 4 + i) * 16;
                v8bf b0 = *(const v8bf*)(WoEt + (size_t)(cb + lq) * 64 + quad * 8);
                v8bf b1 = *(const v8bf*)(WoEt + (size_t)(cb + lq) * 64 + 32 + quad * 8);
                const float bb = bo[cb + lq];
                v4f acc = {bb, bb, bb, bb};
                acc = __builtin_amdgcn_mfma_f32_16x16x32_bf16(a0, b0, acc, 0, 0, 0);
                acc = __builtin_amdgcn_mfma_f32_16x16x32_bf16(a1, b1, acc, 0, 0, 0);
#pragma unroll
                for (int r = 0; r < 4; r++)
                    out[(size_t)(rows0 + quad * 4 + r) * 512 + cb + lq] = acc[r];
            }
        }
    }
}

// ---------------------------------------------------------------- launch
extern "C" void kernel_launch(void* const* d_in, const int* in_sizes, int n_in,
                              void* d_out, int out_size, void* d_ws, size_t ws_size,
                              hipStream_t stream) {
    const float* query = (const float*)d_in[0];
    const float* key   = (const float*)d_in[1];
    // d_in[2] (value) unused: reference projects V from `key`.
    const float* Wq = (const float*)d_in[3];
    const float* bq = (const float*)d_in[4];
    const float* Wk = (const float*)d_in[5];
    const float* bk = (const float*)d_in[6];
    const float* Wv = (const float*)d_in[7];
    const float* bv = (const float*)d_in[8];
    const float* Wo = (const float*)d_in[9];
    const float* bo = (const float*)d_in[10];
    float* out = (float*)d_out;

    char* p = (char*)d_ws;
    __bf16* Qp    = (__bf16*)p; p += (size_t)BS * 64 * 2;          // 1 MB
    __bf16* Kp    = (__bf16*)p; p += (size_t)BS * 64 * 2;          // 1 MB
    __bf16* Vtg   = (__bf16*)p; p += (size_t)BS * 64 * 2;          // 1 MB
    __bf16* Opart = (__bf16*)p; p += (size_t)NCH * BS * 64 * 2;    // 8 MB
    float* lpart = (float*)p;  p += (size_t)NCH * BS * 4;          // 256 KB
    __bf16* WoEt = (__bf16*)p; p += (size_t)64 * 512 * 2;          // 64 KB
    __bf16* Wt   = (__bf16*)p; p += (size_t)3 * 64 * 512 * 2;      // 192 KB
    float* bs    = (float*)p;  p += 768;
    uintptr_t pa = ((uintptr_t)p + 255) & ~(uintptr_t)255;
    unsigned* bar = (unsigned*)pa;        // gen word @ +0, flags @ +256 B

    // Grid sized to guaranteed co-residency (barrier correctness). Host-only
    // occupancy query, cached; safe under graph capture.
    static int nb_s = 0;
    if (nb_s == 0) {
        int perCU = 0;
        if (hipOccupancyMaxActiveBlocksPerMultiprocessor(
                &perCU, reinterpret_cast<const void*>(fused_kernel), 256, 0) != hipSuccess
            || perCU < 1)
            perCU = 1;                                  // 1 block/CU always resident
        nb_s = perCU * 256;                             // 256 CUs on MI355X
        if (nb_s > NVB) nb_s = NVB;
    }

    // Reset gen + all flags (256 B header + 4 KB flags).
    (void)hipMemsetAsync(bar, 0, 256 + 4096, stream);
    fused_kernel<<<nb_s, 256, 0, stream>>>(
        query, key, Wq, bq, Wk, bk, Wv, bv, Wo, bo,
        Qp, Kp, Vtg, Opart, lpart, WoEt, Wt, bs, out, bar);
}

// Round 5
// 177.583 us; speedup vs baseline: 1.4547x; 1.3381x over previous
//
#include <hip/hip_runtime.h>
#include <hip/hip_bf16.h>

// B=4, S=2048, D=512, H=8, DK=DV=64. All heads identical; V projected from
// `key` (faithful bug). tile(o,H)@Wo == o@WoE, WoE[j,d] = sum_h Wo[h*64+j,d].
// Softmax in exp2 domain with FIXED shift M=8. 0.125*log2(e) folded into
// Wq at LDS-staging time.
//
// Round-5 = Round-4 resubmitted verbatim (container infra flake, no data).
// Structure: persistent fusion abandoned (grid barriers cost >=60us each
// on 8-XCD MI355X regardless of design — rounds 1&3). Instead: 2 plain
// dispatches, stream-ordered.
//   A projprep: QKV projection with W^T staged per-block in LDS
//               (prep kernel absorbed); +64 blocks compute WoEt.
//   B attn:     flash attention; per-(b,qt) atomic ticket — the 8th
//               chunk-block to finish merges partials and runs the
//               out-GEMM for its 64-row stripe (outmerge absorbed,
//               overlapped with attention tail; no grid barrier).

#define BB 4
#define SS 2048
#define BS (BB*SS)   // 8192
#define MSHIFT 8.0f
#define NCH 8        // attention chunks per (b,qt)

typedef __bf16 v8bf __attribute__((ext_vector_type(8)));
typedef __bf16 v4bf __attribute__((ext_vector_type(4)));
typedef float  v4f  __attribute__((ext_vector_type(4)));

__device__ inline v8bf cvt8(float4 f0, float4 f1) {   // native v_cvt (RNE)
    v8bf r;
    r[0] = (__bf16)f0.x; r[1] = (__bf16)f0.y; r[2] = (__bf16)f0.z; r[3] = (__bf16)f0.w;
    r[4] = (__bf16)f1.x; r[5] = (__bf16)f1.y; r[6] = (__bf16)f1.z; r[7] = (__bf16)f1.w;
    return r;
}

// ---------------------------------------------------------------- A: proj + prep
// blocks 0..511:    Q tiles.  block vb: rows (vb>>2)*64 + w*16, cols (vb&3)*16.
// blocks 512..1023: K+V tiles (same geometry on `key`).
// blocks 1024..1087: WoEt[d][k] = sum_h Wo[h*64+k][d]  (k = vb-1024).
// W^T slice (16 cols x 512 k) staged in LDS, transposed + scaled on the fly
// (same f32->bf16 conversion as the old prep kernel => bit-identical).
__global__ __launch_bounds__(256) void projprep_kernel(
    const float* __restrict__ query, const float* __restrict__ key,
    const float* __restrict__ Wq, const float* __restrict__ bq,
    const float* __restrict__ Wk, const float* __restrict__ bk,
    const float* __restrict__ Wv, const float* __restrict__ bv,
    const float* __restrict__ Wo,
    __bf16* __restrict__ Qp, __bf16* __restrict__ Kp, __bf16* __restrict__ Vt,
    __bf16* __restrict__ WoEt)
{
    __shared__ __bf16 Ws[2][16][520];      // 33.3 KB; row stride 1040 B (16B-aligned)
    const int t  = threadIdx.x;
    const int vb = blockIdx.x;

    if (vb >= 1024) {                      // WoEt prep
        const int k = vb - 1024;           // 0..63
        for (int d = t; d < 512; d += 256) {
            float sum = 0.f;
#pragma unroll
            for (int h = 0; h < 8; h++) sum += Wo[(size_t)(h * 64 + k) * 512 + d];
            WoEt[d * 64 + k] = (__bf16)sum;
        }
        return;
    }

    const int lane = t & 63, w = t >> 6, lq = lane & 15, quad = lane >> 4;
    const int kind = vb >> 9;              // 0=Q, 1=K+V
    const int v2   = vb & 511;
    const int cb   = (v2 & 3) * 16;
    const int rows = (v2 >> 2) * 64 + w * 16;
    const float qscale = 0.125f * 1.44269504088896340736f;

    // ---- stage W^T slice(s): Ws[s][c][k] = W_s[k][cb+c] (*qscale for Q)
    {
        const int c4 = (t & 3) * 4;
        const int kk = t >> 2;
        if (kind == 0) {
#pragma unroll
            for (int pass = 0; pass < 8; pass++) {
                int k = kk + pass * 64;
                float4 f = *(const float4*)(Wq + (size_t)k * 64 + cb + c4);
                Ws[0][c4 + 0][k] = (__bf16)(f.x * qscale);
                Ws[0][c4 + 1][k] = (__bf16)(f.y * qscale);
                Ws[0][c4 + 2][k] = (__bf16)(f.z * qscale);
                Ws[0][c4 + 3][k] = (__bf16)(f.w * qscale);
            }
        } else {
#pragma unroll
            for (int pass = 0; pass < 8; pass++) {
                int k = kk + pass * 64;
                float4 fk = *(const float4*)(Wk + (size_t)k * 64 + cb + c4);
                float4 fv = *(const float4*)(Wv + (size_t)k * 64 + cb + c4);
                Ws[0][c4 + 0][k] = (__bf16)fk.x;
                Ws[0][c4 + 1][k] = (__bf16)fk.y;
                Ws[0][c4 + 2][k] = (__bf16)fk.z;
                Ws[0][c4 + 3][k] = (__bf16)fk.w;
                Ws[1][c4 + 0][k] = (__bf16)fv.x;
                Ws[1][c4 + 1][k] = (__bf16)fv.y;
                Ws[1][c4 + 2][k] = (__bf16)fv.z;
                Ws[1][c4 + 3][k] = (__bf16)fv.w;
            }
        }
    }
    __syncthreads();

    const float* arow = ((kind == 0) ? query : key) + (size_t)(rows + lq) * 512;

    if (kind == 0) {
        const float bb = bq[cb + lq] * qscale;
        v4f acc = {bb, bb, bb, bb};
#pragma unroll 4
        for (int k0 = 0; k0 < 512; k0 += 32) {
            float4 f0 = *(const float4*)(arow + k0 + quad * 8);
            float4 f1 = *(const float4*)(arow + k0 + quad * 8 + 4);
            v8bf a = cvt8(f0, f1);
            v8bf b = *(const v8bf*)&Ws[0][lq][k0 + quad * 8];
            acc = __builtin_amdgcn_mfma_f32_16x16x32_bf16(a, b, acc, 0, 0, 0);
        }
#pragma unroll
        for (int r = 0; r < 4; r++)
            Qp[(size_t)(rows + quad * 4 + r) * 64 + cb + lq] = (__bf16)acc[r];
    } else {
        const float bk_ = bk[cb + lq], bv_ = bv[cb + lq];
        v4f ak = {bk_, bk_, bk_, bk_}, av = {bv_, bv_, bv_, bv_};
#pragma unroll 4
        for (int k0 = 0; k0 < 512; k0 += 32) {
            float4 f0 = *(const float4*)(arow + k0 + quad * 8);
            float4 f1 = *(const float4*)(arow + k0 + quad * 8 + 4);
            v8bf a  = cvt8(f0, f1);
            v8bf b0 = *(const v8bf*)&Ws[0][lq][k0 + quad * 8];
            v8bf b1 = *(const v8bf*)&Ws[1][lq][k0 + quad * 8];
            ak = __builtin_amdgcn_mfma_f32_16x16x32_bf16(a, b0, ak, 0, 0, 0);
            av = __builtin_amdgcn_mfma_f32_16x16x32_bf16(a, b1, av, 0, 0, 0);
        }
#pragma unroll
        for (int r = 0; r < 4; r++)
            Kp[(size_t)(rows + quad * 4 + r) * 64 + cb + lq] = (__bf16)ak[r];
        v4bf o4; o4[0] = (__bf16)av[0]; o4[1] = (__bf16)av[1];
        o4[2] = (__bf16)av[2]; o4[3] = (__bf16)av[3];
        *(v4bf*)&Vt[(size_t)(cb + lq) * BS + rows + quad * 4] = o4;   // V^T
    }
}

// ---------------------------------------------------------------- B: attn + fused epilogue
// Grid (128, NCH). Attention body identical to the 150us-verified kernel.
// After partial writes, each chunk-block tickets cnt[b*32+qt] with ACQ_REL
// (agent scope). The 8th arriver — release/acquire chain makes all chunks'
// Opart/lpart globally visible — merges the 8 partials and runs the
// out-GEMM for its 64-row stripe (same math/order as old outmerge).
__global__ __launch_bounds__(256) void attn_kernel(
    const __bf16* __restrict__ Qp,  // [BS][64], scale folded
    const __bf16* __restrict__ Kp,  // [BS][64]
    const __bf16* __restrict__ Vt,  // [64][BS]
    __bf16* __restrict__ Opart,     // [NCH][BS][64]
    float* __restrict__ lpart,      // [NCH][BS]
    const __bf16* __restrict__ WoEt,// [512][64]
    const float* __restrict__ bo,
    float* __restrict__ out,
    unsigned* __restrict__ cnt)     // [128], zeroed per launch
{
    __shared__ __bf16 Ks[64][72];
    __shared__ __bf16 Vs[64][72];
    __shared__ __bf16 Ps[4][16][72];
    __shared__ unsigned arr_s;

    const int t    = threadIdx.x;
    const int lane = t & 63;
    const int w    = t >> 6;
    const int b    = blockIdx.x & 3;
    const int qt   = 31 - (blockIdx.x >> 2);   // longest work first
    const int c    = blockIdx.y;
    const int qbase = qt * 64;
    const int L    = qbase + 64;
    const int cs   = ((L + NCH * 64 - 1) / (NCH * 64)) * 64;
    const int klo  = c * cs;
    const int khi  = min(klo + cs, L);         // multiple of 64
    const size_t bbase = (size_t)b * SS;

    const int lq   = lane & 15;
    const int quad = lane >> 4;
    const int qrow_w = qbase + w * 16;
    const int wmax   = qrow_w + 15;

    const size_t qoff = (bbase + qrow_w + lq) * 64;
    v8bf qa0 = *(const v8bf*)(Qp + qoff + quad * 8);
    v8bf qa1 = *(const v8bf*)(Qp + qoff + 32 + quad * 8);

    v8bf ones;
#pragma unroll
    for (int i = 0; i < 8; i++) ones[i] = (__bf16)1.0f;

    v4f o[4] = {};
    v4f lacc = {};

    const int ky0 = t >> 3,         dd0 = (t & 7) * 8;       // rows 0..31
    const int ky1 = (t + 256) >> 3, dd1 = dd0;               // rows 32..63

    v8bf kpre0, kpre1, vpre0, vpre1;
    if (klo < khi) {
        kpre0 = *(const v8bf*)(Kp + (bbase + klo + ky0) * 64 + dd0);
        kpre1 = *(const v8bf*)(Kp + (bbase + klo + ky1) * 64 + dd1);
        vpre0 = *(const v8bf*)(Vt + (size_t)ky0 * BS + bbase + klo + dd0);
        vpre1 = *(const v8bf*)(Vt + (size_t)ky1 * BS + bbase + klo + dd1);
    }

    for (int kb = klo; kb < khi; kb += 64) {
        __syncthreads();                       // previous tile's readers done
        *(v8bf*)&Ks[ky0][dd0] = kpre0;
        *(v8bf*)&Ks[ky1][dd1] = kpre1;
        *(v8bf*)&Vs[ky0][dd0] = vpre0;
        *(v8bf*)&Vs[ky1][dd1] = vpre1;
        if (kb + 64 < khi) {                   // prefetch next tile
            kpre0 = *(const v8bf*)(Kp + (bbase + kb + 64 + ky0) * 64 + dd0);
            kpre1 = *(const v8bf*)(Kp + (bbase + kb + 64 + ky1) * 64 + dd1);
            vpre0 = *(const v8bf*)(Vt + (size_t)ky0 * BS + bbase + kb + 64 + dd0);
            vpre1 = *(const v8bf*)(Vt + (size_t)ky1 * BS + bbase + kb + 64 + dd1);
        }
        __syncthreads();
        if (kb > wmax) continue;               // wave fully masked (uniform)

        // ---- S = Q K^T
        v4f s[4];
#pragma unroll
        for (int n = 0; n < 4; n++) {
            v8bf ka  = *(const v8bf*)&Ks[n * 16 + lq][quad * 8];
            v8bf kb2 = *(const v8bf*)&Ks[n * 16 + lq][32 + quad * 8];
            v4f z = {0.f, 0.f, 0.f, 0.f};
            z    = __builtin_amdgcn_mfma_f32_16x16x32_bf16(qa0, ka,  z, 0, 0, 0);
            s[n] = __builtin_amdgcn_mfma_f32_16x16x32_bf16(qa1, kb2, z, 0, 0, 0);
        }

        // ---- P = exp2(s - 8), causal-masked; to LDS (C->A relayout)
        const int row0 = qrow_w + quad * 4;
        const int col0 = kb + lq;
#pragma unroll
        for (int n = 0; n < 4; n++)
#pragma unroll
            for (int r = 0; r < 4; r++) {
                float e = exp2f(s[n][r] - MSHIFT);
                e = (col0 + n * 16 > row0 + r) ? 0.f : e;
                Ps[w][quad * 4 + r][n * 16 + lq] = (__bf16)e;
            }
        v8bf pa0 = *(const v8bf*)&Ps[w][lq][quad * 8];
        v8bf pa1 = *(const v8bf*)&Ps[w][lq][32 + quad * 8];

        // ---- l += P @ ones
        lacc = __builtin_amdgcn_mfma_f32_16x16x32_bf16(pa0, ones, lacc, 0, 0, 0);
        lacc = __builtin_amdgcn_mfma_f32_16x16x32_bf16(pa1, ones, lacc, 0, 0, 0);

        // ---- O += P V
#pragma unroll
        for (int vt2 = 0; vt2 < 4; vt2++) {
            v8bf vb0 = *(const v8bf*)&Vs[vt2 * 16 + lq][quad * 8];
            v8bf vb1 = *(const v8bf*)&Vs[vt2 * 16 + lq][32 + quad * 8];
            o[vt2] = __builtin_amdgcn_mfma_f32_16x16x32_bf16(pa0, vb0, o[vt2], 0, 0, 0);
            o[vt2] = __builtin_amdgcn_mfma_f32_16x16x32_bf16(pa1, vb1, o[vt2], 0, 0, 0);
        }
    }

    // ---- write partials (empty chunks write o=0, l=0 — merge-neutral)
#pragma unroll
    for (int vt2 = 0; vt2 < 4; vt2++)
#pragma unroll
        for (int r = 0; r < 4; r++) {
            int qrow = qrow_w + quad * 4 + r;
            Opart[((size_t)c * BS + bbase + qrow) * 64 + vt2 * 16 + lq] = (__bf16)o[vt2][r];
        }
    if (lq < 4) {
        int qrow = qrow_w + quad * 4 + lq;
        lpart[(size_t)c * BS + bbase + qrow] = lacc[lq];
    }

    // ---- atomic ticket: 8th arriver owns the stripe epilogue
    __syncthreads();   // drains all waves' stores (vmcnt(0) before s_barrier)
    if (t == 0)
        arr_s = __hip_atomic_fetch_add(&cnt[b * 32 + qt], 1u,
                                       __ATOMIC_ACQ_REL, __HIP_MEMORY_SCOPE_AGENT);
    __syncthreads();
    if (arr_s != NCH - 1u) return;

    // ---- merge 8 chunks -> Os (bf16, normalized); same math/order as outmerge
    __bf16 (&Os)[64][72] = Ks;                 // k-loop done; reuse LDS
    {
        const int row = t >> 2;                // 0..63
        const int d0  = (t & 3) * 16;          // 16 cols per thread
        const size_t grow = bbase + qbase + row;
        float den = 0.f;
#pragma unroll
        for (int c2 = 0; c2 < NCH; c2++) den += lpart[(size_t)c2 * BS + grow];
        const float inv = 1.f / den;
        float m[16] = {0.f, 0.f, 0.f, 0.f, 0.f, 0.f, 0.f, 0.f,
                       0.f, 0.f, 0.f, 0.f, 0.f, 0.f, 0.f, 0.f};
#pragma unroll
        for (int c2 = 0; c2 < NCH; c2++) {
            const __bf16* src = Opart + ((size_t)c2 * BS + grow) * 64 + d0;
            v8bf u0 = *(const v8bf*)src;
            v8bf u1 = *(const v8bf*)(src + 8);
#pragma unroll
            for (int j = 0; j < 8; j++) { m[j] += (float)u0[j]; m[8 + j] += (float)u1[j]; }
        }
#pragma unroll
        for (int j = 0; j < 16; j++) Os[row][d0 + j] = (__bf16)(m[j] * inv);
    }
    __syncthreads();

    // ---- out-GEMM: wave w does rows qbase+w*16.., all 32 col-tiles
    {
        v8bf a0 = *(const v8bf*)&Os[w * 16 + lq][quad * 8];
        v8bf a1 = *(const v8bf*)&Os[w * 16 + lq][32 + quad * 8];
        const int orow = qbase + w * 16;
#pragma unroll 4
        for (int i = 0; i < 32; i++) {
            const int cb2 = i * 16;
            v8bf b0 = *(const v8bf*)(WoEt + (size_t)(cb2 + lq) * 64 + quad * 8);
            v8bf b1 = *(const v8bf*)(WoEt + (size_t)(cb2 + lq) * 64 + 32 + quad * 8);
            const float bb2 = bo[cb2 + lq];
            v4f acc = {bb2, bb2, bb2, bb2};
            acc = __builtin_amdgcn_mfma_f32_16x16x32_bf16(a0, b0, acc, 0, 0, 0);
            acc = __builtin_amdgcn_mfma_f32_16x16x32_bf16(a1, b1, acc, 0, 0, 0);
#pragma unroll
            for (int r = 0; r < 4; r++)
                out[(size_t)(bbase + orow + quad * 4 + r) * 512 + cb2 + lq] = acc[r];
        }
    }
}

// ---------------------------------------------------------------- launch
extern "C" void kernel_launch(void* const* d_in, const int* in_sizes, int n_in,
                              void* d_out, int out_size, void* d_ws, size_t ws_size,
                              hipStream_t stream) {
    const float* query = (const float*)d_in[0];
    const float* key   = (const float*)d_in[1];
    // d_in[2] (value) unused: reference projects V from `key`.
    const float* Wq = (const float*)d_in[3];
    const float* bq = (const float*)d_in[4];
    const float* Wk = (const float*)d_in[5];
    const float* bk = (const float*)d_in[6];
    const float* Wv = (const float*)d_in[7];
    const float* bv = (const float*)d_in[8];
    const float* Wo = (const float*)d_in[9];
    const float* bo = (const float*)d_in[10];
    float* out = (float*)d_out;

    char* p = (char*)d_ws;
    __bf16* Qp    = (__bf16*)p; p += (size_t)BS * 64 * 2;          // 1 MB
    __bf16* Kp    = (__bf16*)p; p += (size_t)BS * 64 * 2;          // 1 MB
    __bf16* Vtg   = (__bf16*)p; p += (size_t)BS * 64 * 2;          // 1 MB
    __bf16* Opart = (__bf16*)p; p += (size_t)NCH * BS * 64 * 2;    // 8 MB
    float* lpart = (float*)p;  p += (size_t)NCH * BS * 4;          // 256 KB
    __bf16* WoEt = (__bf16*)p; p += (size_t)64 * 512 * 2;          // 64 KB
    uintptr_t pa = ((uintptr_t)p + 255) & ~(uintptr_t)255;
    unsigned* cnt = (unsigned*)pa;                                  // 128 u32

    (void)hipMemsetAsync(cnt, 0, 512, stream);                      // per-launch reset
    projprep_kernel<<<1088, 256, 0, stream>>>(
        query, key, Wq, bq, Wk, bk, Wv, bv, Wo, Qp, Kp, Vtg, WoEt);
    attn_kernel<<<dim3(128, NCH), 256, 0, stream>>>(
        Qp, Kp, Vtg, Opart, lpart, WoEt, bo, out, cnt);
}

// Round 6
// 162.469 us; speedup vs baseline: 1.5900x; 1.0930x over previous
//
#include <hip/hip_runtime.h>
#include <hip/hip_bf16.h>

// B=4, S=2048, D=512, H=8, DK=DV=64. All heads identical; V projected from
// `key` (faithful bug). tile(o,H)@Wo == o@WoE, WoE[j,d] = sum_h Wo[h*64+j,d].
// Softmax in exp2 domain with FIXED shift M=8. 0.125*log2(e) folded into
// Wq at LDS-staging time.
//
// Round-6: split-K attention abandoned. Round-5 counters showed the
// ticket-epilogue attn at 61us with 1.7% MfmaUtil — the per-block
// agent-scope ACQ_REL atomics (L2 writeback/inv per block) + 16 MB of
// partial round-trip traffic were the cost, not the compute.
// New structure: 128 stripes (b,qt) x 256 CUs — each block owns one full
// stripe end-to-end: full K-range flash attention (accumulators stay in
// registers), in-register normalize, fused out-GEMM. No atomics, no
// partials, no memset. 2 dispatches total.

#define BB 4
#define SS 2048
#define BS (BB*SS)   // 8192
#define MSHIFT 8.0f

typedef __bf16 v8bf __attribute__((ext_vector_type(8)));
typedef __bf16 v4bf __attribute__((ext_vector_type(4)));
typedef float  v4f  __attribute__((ext_vector_type(4)));

__device__ inline v8bf cvt8(float4 f0, float4 f1) {   // native v_cvt (RNE)
    v8bf r;
    r[0] = (__bf16)f0.x; r[1] = (__bf16)f0.y; r[2] = (__bf16)f0.z; r[3] = (__bf16)f0.w;
    r[4] = (__bf16)f1.x; r[5] = (__bf16)f1.y; r[6] = (__bf16)f1.z; r[7] = (__bf16)f1.w;
    return r;
}

// ---------------------------------------------------------------- A: proj + prep
// blocks 0..511:    Q tiles.  block vb: rows (vb>>2)*64 + w*16, cols (vb&3)*16.
// blocks 512..1023: K+V tiles (same geometry on `key`).
// blocks 1024..1087: WoEt[d][k] = sum_h Wo[h*64+k][d]  (k = vb-1024).
// W^T slice (16 cols x 512 k) staged in LDS, transposed + scaled on the fly.
// (verified in Round 5: passed, absmax 0.00390625)
__global__ __launch_bounds__(256) void projprep_kernel(
    const float* __restrict__ query, const float* __restrict__ key,
    const float* __restrict__ Wq, const float* __restrict__ bq,
    const float* __restrict__ Wk, const float* __restrict__ bk,
    const float* __restrict__ Wv, const float* __restrict__ bv,
    const float* __restrict__ Wo,
    __bf16* __restrict__ Qp, __bf16* __restrict__ Kp, __bf16* __restrict__ Vt,
    __bf16* __restrict__ WoEt)
{
    __shared__ __bf16 Ws[2][16][520];      // 33.3 KB; row stride 1040 B (16B-aligned)
    const int t  = threadIdx.x;
    const int vb = blockIdx.x;

    if (vb >= 1024) {                      // WoEt prep
        const int k = vb - 1024;           // 0..63
        for (int d = t; d < 512; d += 256) {
            float sum = 0.f;
#pragma unroll
            for (int h = 0; h < 8; h++) sum += Wo[(size_t)(h * 64 + k) * 512 + d];
            WoEt[d * 64 + k] = (__bf16)sum;
        }
        return;
    }

    const int lane = t & 63, w = t >> 6, lq = lane & 15, quad = lane >> 4;
    const int kind = vb >> 9;              // 0=Q, 1=K+V
    const int v2   = vb & 511;
    const int cb   = (v2 & 3) * 16;
    const int rows = (v2 >> 2) * 64 + w * 16;
    const float qscale = 0.125f * 1.44269504088896340736f;

    // ---- stage W^T slice(s): Ws[s][c][k] = W_s[k][cb+c] (*qscale for Q)
    {
        const int c4 = (t & 3) * 4;
        const int kk = t >> 2;
        if (kind == 0) {
#pragma unroll
            for (int pass = 0; pass < 8; pass++) {
                int k = kk + pass * 64;
                float4 f = *(const float4*)(Wq + (size_t)k * 64 + cb + c4);
                Ws[0][c4 + 0][k] = (__bf16)(f.x * qscale);
                Ws[0][c4 + 1][k] = (__bf16)(f.y * qscale);
                Ws[0][c4 + 2][k] = (__bf16)(f.z * qscale);
                Ws[0][c4 + 3][k] = (__bf16)(f.w * qscale);
            }
        } else {
#pragma unroll
            for (int pass = 0; pass < 8; pass++) {
                int k = kk + pass * 64;
                float4 fk = *(const float4*)(Wk + (size_t)k * 64 + cb + c4);
                float4 fv = *(const float4*)(Wv + (size_t)k * 64 + cb + c4);
                Ws[0][c4 + 0][k] = (__bf16)fk.x;
                Ws[0][c4 + 1][k] = (__bf16)fk.y;
                Ws[0][c4 + 2][k] = (__bf16)fk.z;
                Ws[0][c4 + 3][k] = (__bf16)fk.w;
                Ws[1][c4 + 0][k] = (__bf16)fv.x;
                Ws[1][c4 + 1][k] = (__bf16)fv.y;
                Ws[1][c4 + 2][k] = (__bf16)fv.z;
                Ws[1][c4 + 3][k] = (__bf16)fv.w;
            }
        }
    }
    __syncthreads();

    const float* arow = ((kind == 0) ? query : key) + (size_t)(rows + lq) * 512;

    if (kind == 0) {
        const float bb = bq[cb + lq] * qscale;
        v4f acc = {bb, bb, bb, bb};
#pragma unroll 4
        for (int k0 = 0; k0 < 512; k0 += 32) {
            float4 f0 = *(const float4*)(arow + k0 + quad * 8);
            float4 f1 = *(const float4*)(arow + k0 + quad * 8 + 4);
            v8bf a = cvt8(f0, f1);
            v8bf b = *(const v8bf*)&Ws[0][lq][k0 + quad * 8];
            acc = __builtin_amdgcn_mfma_f32_16x16x32_bf16(a, b, acc, 0, 0, 0);
        }
#pragma unroll
        for (int r = 0; r < 4; r++)
            Qp[(size_t)(rows + quad * 4 + r) * 64 + cb + lq] = (__bf16)acc[r];
    } else {
        const float bk_ = bk[cb + lq], bv_ = bv[cb + lq];
        v4f ak = {bk_, bk_, bk_, bk_}, av = {bv_, bv_, bv_, bv_};
#pragma unroll 4
        for (int k0 = 0; k0 < 512; k0 += 32) {
            float4 f0 = *(const float4*)(arow + k0 + quad * 8);
            float4 f1 = *(const float4*)(arow + k0 + quad * 8 + 4);
            v8bf a  = cvt8(f0, f1);
            v8bf b0 = *(const v8bf*)&Ws[0][lq][k0 + quad * 8];
            v8bf b1 = *(const v8bf*)&Ws[1][lq][k0 + quad * 8];
            ak = __builtin_amdgcn_mfma_f32_16x16x32_bf16(a, b0, ak, 0, 0, 0);
            av = __builtin_amdgcn_mfma_f32_16x16x32_bf16(a, b1, av, 0, 0, 0);
        }
#pragma unroll
        for (int r = 0; r < 4; r++)
            Kp[(size_t)(rows + quad * 4 + r) * 64 + cb + lq] = (__bf16)ak[r];
        v4bf o4; o4[0] = (__bf16)av[0]; o4[1] = (__bf16)av[1];
        o4[2] = (__bf16)av[2]; o4[3] = (__bf16)av[3];
        *(v4bf*)&Vt[(size_t)(cb + lq) * BS + rows + quad * 4] = o4;   // V^T
    }
}

// ---------------------------------------------------------------- B: full-stripe attn + out-GEMM
// Grid 128 = 4 b x 32 qt; one block per 64-row stripe, one CU per block.
// Block processes its ENTIRE causal K-range (qt+1 tiles of 64 keys):
// accumulators o[4]/lacc live in registers for the whole range, so no
// split-K partials exist. Epilogue: in-register normalize -> LDS -> the
// stripe's 64x512 out-GEMM. No atomics anywhere.
__global__ __launch_bounds__(256) void attn_kernel(
    const __bf16* __restrict__ Qp,  // [BS][64], scale folded
    const __bf16* __restrict__ Kp,  // [BS][64]
    const __bf16* __restrict__ Vt,  // [64][BS]
    const __bf16* __restrict__ WoEt,// [512][64]
    const float* __restrict__ bo,
    float* __restrict__ out)
{
    __shared__ __bf16 Ks[64][72];
    __shared__ __bf16 Vs[64][72];
    __shared__ __bf16 Ps[4][16][72];

    const int t    = threadIdx.x;
    const int lane = t & 63;
    const int w    = t >> 6;
    const int b    = blockIdx.x & 3;
    const int qt   = blockIdx.x >> 2;          // 0..31
    const int qbase = qt * 64;
    const int L    = qbase + 64;               // causal K-range
    const size_t bbase = (size_t)b * SS;

    const int lq   = lane & 15;
    const int quad = lane >> 4;
    const int qrow_w = qbase + w * 16;

    const size_t qoff = (bbase + qrow_w + lq) * 64;
    v8bf qa0 = *(const v8bf*)(Qp + qoff + quad * 8);
    v8bf qa1 = *(const v8bf*)(Qp + qoff + 32 + quad * 8);

    v8bf ones;
#pragma unroll
    for (int i = 0; i < 8; i++) ones[i] = (__bf16)1.0f;

    v4f o[4] = {};
    v4f lacc = {};

    const int ky0 = t >> 3,         dd0 = (t & 7) * 8;       // rows 0..31
    const int ky1 = (t + 256) >> 3, dd1 = dd0;               // rows 32..63

    v8bf kpre0 = *(const v8bf*)(Kp + (bbase + ky0) * 64 + dd0);
    v8bf kpre1 = *(const v8bf*)(Kp + (bbase + ky1) * 64 + dd1);
    v8bf vpre0 = *(const v8bf*)(Vt + (size_t)ky0 * BS + bbase + dd0);
    v8bf vpre1 = *(const v8bf*)(Vt + (size_t)ky1 * BS + bbase + dd1);

    for (int kb = 0; kb < L; kb += 64) {
        __syncthreads();                       // previous tile's readers done
        *(v8bf*)&Ks[ky0][dd0] = kpre0;
        *(v8bf*)&Ks[ky1][dd1] = kpre1;
        *(v8bf*)&Vs[ky0][dd0] = vpre0;
        *(v8bf*)&Vs[ky1][dd1] = vpre1;
        if (kb + 64 < L) {                     // prefetch next tile
            kpre0 = *(const v8bf*)(Kp + (bbase + kb + 64 + ky0) * 64 + dd0);
            kpre1 = *(const v8bf*)(Kp + (bbase + kb + 64 + ky1) * 64 + dd1);
            vpre0 = *(const v8bf*)(Vt + (size_t)ky0 * BS + bbase + kb + 64 + dd0);
            vpre1 = *(const v8bf*)(Vt + (size_t)ky1 * BS + bbase + kb + 64 + dd1);
        }
        __syncthreads();

        // ---- S = Q K^T
        v4f s[4];
#pragma unroll
        for (int n = 0; n < 4; n++) {
            v8bf ka  = *(const v8bf*)&Ks[n * 16 + lq][quad * 8];
            v8bf kb2 = *(const v8bf*)&Ks[n * 16 + lq][32 + quad * 8];
            v4f z = {0.f, 0.f, 0.f, 0.f};
            z    = __builtin_amdgcn_mfma_f32_16x16x32_bf16(qa0, ka,  z, 0, 0, 0);
            s[n] = __builtin_amdgcn_mfma_f32_16x16x32_bf16(qa1, kb2, z, 0, 0, 0);
        }

        // ---- P = exp2(s - 8), causal-masked; to LDS (C->A relayout)
        const int row0 = qrow_w + quad * 4;
        const int col0 = kb + lq;
#pragma unroll
        for (int n = 0; n < 4; n++)
#pragma unroll
            for (int r = 0; r < 4; r++) {
                float e = exp2f(s[n][r] - MSHIFT);
                e = (col0 + n * 16 > row0 + r) ? 0.f : e;
                Ps[w][quad * 4 + r][n * 16 + lq] = (__bf16)e;
            }
        v8bf pa0 = *(const v8bf*)&Ps[w][lq][quad * 8];
        v8bf pa1 = *(const v8bf*)&Ps[w][lq][32 + quad * 8];

        // ---- l += P @ ones
        lacc = __builtin_amdgcn_mfma_f32_16x16x32_bf16(pa0, ones, lacc, 0, 0, 0);
        lacc = __builtin_amdgcn_mfma_f32_16x16x32_bf16(pa1, ones, lacc, 0, 0, 0);

        // ---- O += P V
#pragma unroll
        for (int vt2 = 0; vt2 < 4; vt2++) {
            v8bf vb0 = *(const v8bf*)&Vs[vt2 * 16 + lq][quad * 8];
            v8bf vb1 = *(const v8bf*)&Vs[vt2 * 16 + lq][32 + quad * 8];
            o[vt2] = __builtin_amdgcn_mfma_f32_16x16x32_bf16(pa0, vb0, o[vt2], 0, 0, 0);
            o[vt2] = __builtin_amdgcn_mfma_f32_16x16x32_bf16(pa1, vb1, o[vt2], 0, 0, 0);
        }
    }

    // ---- epilogue: normalize in registers, stage to LDS (reuse Ks as Os)
    __syncthreads();                           // last tile's Ks/Vs readers done
    __bf16 (&Os)[64][72] = Ks;
#pragma unroll
    for (int r = 0; r < 4; r++) {
        const float inv = 1.f / lacc[r];       // row sum (identical across lq)
#pragma unroll
        for (int vt2 = 0; vt2 < 4; vt2++)
            Os[w * 16 + quad * 4 + r][vt2 * 16 + lq] = (__bf16)(o[vt2][r] * inv);
    }
    __syncthreads();

    // ---- out-GEMM: wave w does rows qbase+w*16.., all 32 col-tiles
    {
        v8bf a0 = *(const v8bf*)&Os[w * 16 + lq][quad * 8];
        v8bf a1 = *(const v8bf*)&Os[w * 16 + lq][32 + quad * 8];
        const size_t orow = bbase + qbase + w * 16;
#pragma unroll 4
        for (int i = 0; i < 32; i++) {
            const int cb2 = i * 16;
            v8bf b0 = *(const v8bf*)(WoEt + (size_t)(cb2 + lq) * 64 + quad * 8);
            v8bf b1 = *(const v8bf*)(WoEt + (size_t)(cb2 + lq) * 64 + 32 + quad * 8);
            const float bb2 = bo[cb2 + lq];
            v4f acc = {bb2, bb2, bb2, bb2};
            acc = __builtin_amdgcn_mfma_f32_16x16x32_bf16(a0, b0, acc, 0, 0, 0);
            acc = __builtin_amdgcn_mfma_f32_16x16x32_bf16(a1, b1, acc, 0, 0, 0);
#pragma unroll
            for (int r = 0; r < 4; r++)
                out[(orow + quad * 4 + r) * 512 + cb2 + lq] = acc[r];
        }
    }
}

// ---------------------------------------------------------------- launch
extern "C" void kernel_launch(void* const* d_in, const int* in_sizes, int n_in,
                              void* d_out, int out_size, void* d_ws, size_t ws_size,
                              hipStream_t stream) {
    const float* query = (const float*)d_in[0];
    const float* key   = (const float*)d_in[1];
    // d_in[2] (value) unused: reference projects V from `key`.
    const float* Wq = (const float*)d_in[3];
    const float* bq = (const float*)d_in[4];
    const float* Wk = (const float*)d_in[5];
    const float* bk = (const float*)d_in[6];
    const float* Wv = (const float*)d_in[7];
    const float* bv = (const float*)d_in[8];
    const float* Wo = (const float*)d_in[9];
    const float* bo = (const float*)d_in[10];
    float* out = (float*)d_out;

    char* p = (char*)d_ws;
    __bf16* Qp   = (__bf16*)p; p += (size_t)BS * 64 * 2;           // 1 MB
    __bf16* Kp   = (__bf16*)p; p += (size_t)BS * 64 * 2;           // 1 MB
    __bf16* Vtg  = (__bf16*)p; p += (size_t)BS * 64 * 2;           // 1 MB
    __bf16* WoEt = (__bf16*)p; p += (size_t)64 * 512 * 2;          // 64 KB

    projprep_kernel<<<1088, 256, 0, stream>>>(
        query, key, Wq, bq, Wk, bk, Wv, bv, Wo, Qp, Kp, Vtg, WoEt);
    attn_kernel<<<128, 256, 0, stream>>>(Qp, Kp, Vtg, WoEt, bo, out);
}